// Round 7
// baseline (135.057 us; speedup 1.0000x reference)
//
#include <hip/hip_runtime.h>

#define NEGV -1e30f

// Problem constants (fixed by setup_inputs)
constexpr int Bn = 8, Ci = 64, Hn = 64, Wn = 64, Co = 64;
constexpr int HW = Hn * Wn;
constexpr int COB = 2;   // co per thread
constexpr int CIU = 4;   // ci unroll: 12 float4 loads batched per super-iteration

// Thread = 4 output cols (float4) x 2 co; wave = 4 rows x 64 cols.
// Grid = 32 cog x 4 hg x 8 b = 1024 blocks = 4 blocks/CU = 16 waves/CU.
// R6 diagnosis: latency-bound (VALU 37%, TA 7% real). Fix: unroll ci x4,
// batch all 12 loads in one branch-free block so the scheduler keeps them
// in flight (staggered vmcnt) across the 4 compute stages.
__device__ __forceinline__ float dpp_prev(float v) {  // lane i <- lane i-1 within 16-lane row
    return __int_as_float(__builtin_amdgcn_update_dpp(0, __float_as_int(v), 0x111, 0xF, 0xF, true));
}
__device__ __forceinline__ float dpp_next(float v) {  // lane i <- lane i+1 within 16-lane row
    return __int_as_float(__builtin_amdgcn_update_dpp(0, __float_as_int(v), 0x101, 0xF, 0xF, true));
}

__global__ __launch_bounds__(256, 4)
void maxconv_kernel(const float* __restrict__ x, const float* __restrict__ wt,
                    float* __restrict__ out) {
    const int bid  = blockIdx.x;
    const int b    = bid & 7;          // XCD swizzle: batch plane b pinned to one XCD's L2
    const int rest = bid >> 3;
    const int cog  = rest & 31;        // 32 co-groups
    const int hg   = rest >> 5;        // 0..3
    const int lane = threadIdx.x & 63;
    const int wv   = threadIdx.x >> 6; // 0..3
    const int r    = lane >> 4;        // row within wave
    const int g    = lane & 15;        // col group (matches 16-lane DPP row)
    const int h    = hg * 16 + wv * 4 + r;   // output row
    const int c0   = g * 4;                  // first output col
    const int co0  = cog * COB;

    const bool topE = (h == 0), botE = (h == Hn - 1);
    const bool gL = (g == 0), gR = (g == 15);

    const float* pb = x + (size_t)b * Ci * HW;
    int v0 = h * Wn + c0;              // element offsets, bumped by CIU*HW per iter
    int vm = v0 - (topE ? 0 : Wn);     // clamped (value fixed by cndmask below)
    int vp = v0 + (botE ? 0 : Wn);

    float acc[COB][4];
#pragma unroll
    for (int c = 0; c < COB; c++)
#pragma unroll
        for (int p = 0; p < 4; p++) acc[c][p] = NEGV;

#pragma unroll 1
    for (int ci = 0; ci < Ci; ci += CIU) {
        // ---- batch: 12 independent loads, no value-dependent ops between ----
        float4 am[CIU], a0[CIU], ap[CIU];
#pragma unroll
        for (int u = 0; u < CIU; u++) {
            am[u] = *(const float4*)(pb + vm + u * HW);   // row h-1
            a0[u] = *(const float4*)(pb + v0 + u * HW);   // row h
            ap[u] = *(const float4*)(pb + vp + u * HW);   // row h+1
        }
        vm += CIU * HW; v0 += CIU * HW; vp += CIU * HW;

        // ---- consume: 4 compute stages; scheduler staggers vmcnt waits ----
#pragma unroll
        for (int u = 0; u < CIU; u++) {
            float4 wm = am[u], w0 = a0[u], wp4 = ap[u];
            // row-edge fixup BEFORE DPP so shifted-in neighbors inherit NEG
            if (topE) { wm.x = NEGV; wm.y = NEGV; wm.z = NEGV; wm.w = NEGV; }
            if (botE) { wp4.x = NEGV; wp4.y = NEGV; wp4.z = NEGV; wp4.w = NEGV; }

            // col halo from adjacent lanes (same 16-lane DPP row = same image row)
            float Lm = dpp_prev(wm.w), L0 = dpp_prev(w0.w), Lp = dpp_prev(wp4.w);
            float Rm = dpp_next(wm.x), R0 = dpp_next(w0.x), Rp = dpp_next(wp4.x);
            if (gL) { Lm = NEGV; L0 = NEGV; Lp = NEGV; }   // plane left edge
            if (gR) { Rm = NEGV; R0 = NEGV; Rp = NEGV; }   // plane right edge

            const float um[6] = { Lm, wm.x, wm.y, wm.z, wm.w, Rm };
            const float u0[6] = { L0, w0.x, w0.y, w0.z, w0.w, R0 };
            const float up[6] = { Lp, wp4.x, wp4.y, wp4.z, wp4.w, Rp };

#pragma unroll
            for (int c = 0; c < COB; c++) {
                // block-uniform address -> scalar weight reads, consumed inline
                const float* wp = wt + ((size_t)(co0 + c) * Ci + (ci + u)) * 9;
                const float q0 = wp[0], q1 = wp[1], q2 = wp[2];
                const float q3 = wp[3], q4 = wp[4], q5 = wp[5];
                const float q6 = wp[6], q7 = wp[7], q8 = wp[8];
#pragma unroll
                for (int p = 0; p < 4; p++) {
                    float t0 = um[p]     + q0;
                    float t1 = um[p + 1] + q1;
                    float t2 = um[p + 2] + q2;
                    float t3 = u0[p]     + q3;
                    float t4 = u0[p + 1] + q4;
                    float t5 = u0[p + 2] + q5;
                    float t6 = up[p]     + q6;
                    float t7 = up[p + 1] + q7;
                    float t8 = up[p + 2] + q8;
                    float a = acc[c][p];
                    a = fmaxf(a, fmaxf(t0, t1));   // v_max3_f32
                    a = fmaxf(a, fmaxf(t2, t3));
                    a = fmaxf(a, fmaxf(t4, t5));
                    a = fmaxf(a, fmaxf(t6, t7));
                    a = fmaxf(a, t8);
                    acc[c][p] = a;
                }
            }
        }
    }

    // store: float4 per co, 16 B/lane
#pragma unroll
    for (int c = 0; c < COB; c++) {
        float4 v = make_float4(acc[c][0], acc[c][1], acc[c][2], acc[c][3]);
        *(float4*)(out + (((size_t)b * Co + co0 + c) * Hn + h) * Wn + c0) = v;
    }
}

extern "C" void kernel_launch(void* const* d_in, const int* in_sizes, int n_in,
                              void* d_out, int out_size, void* d_ws, size_t ws_size,
                              hipStream_t stream) {
    const float* x  = (const float*)d_in[0];
    const float* wt = (const float*)d_in[1];
    float* out = (float*)d_out;

    maxconv_kernel<<<dim3(1024), 256, 0, stream>>>(x, wt, out);
}